// Round 1
// baseline (5430.618 us; speedup 1.0000x reference)
//
#include <hip/hip_runtime.h>
#include <cstdint>
#include <cstddef>

#define T_SEQ 4096
#define HID 3072
#define NH 16
#define DKH 128
#define KD 2048
#define VD 2048
#define N_QKVZ 8192
#define CONV_CH 6144
#define MROWS 8192  // B*T

typedef unsigned short u16;
typedef unsigned int u32;

typedef __attribute__((ext_vector_type(8))) short bf16x8;
typedef __attribute__((ext_vector_type(4))) float f32x4;

__device__ __forceinline__ float bf2f(u16 u){ u32 t=((u32)u)<<16; float f; __builtin_memcpy(&f,&t,4); return f; }
__device__ __forceinline__ float bflo(u32 u){ u32 t=u<<16; float f; __builtin_memcpy(&f,&t,4); return f; }
__device__ __forceinline__ float bfhi(u32 u){ u32 t=u&0xffff0000u; float f; __builtin_memcpy(&f,&t,4); return f; }
__device__ __forceinline__ u16 f2bf(float f){ u32 i; __builtin_memcpy(&i,&f,4); return (u16)((i + 0x7fffu + ((i>>16)&1u))>>16); }

// ---------- cast f32 -> bf16 (flat) ----------
__global__ void k_cast(const float* __restrict__ in, u16* __restrict__ out, int n4){
    int stride = gridDim.x*blockDim.x;
    for (int i = blockIdx.x*blockDim.x + threadIdx.x; i < n4; i += stride){
        float4 v = ((const float4*)in)[i];
        u32 lo = (u32)f2bf(v.x) | ((u32)f2bf(v.y)<<16);
        u32 hi = (u32)f2bf(v.z) | ((u32)f2bf(v.w)<<16);
        ((uint2*)out)[i] = make_uint2(lo,hi);
    }
}

// ---------- transpose + cast: in[R][C] f32 -> out[C][R] bf16 ----------
__global__ void k_transpose_cast(const float* __restrict__ in, u16* __restrict__ out, int R, int C){
    __shared__ u16 tile[32][33];
    int nbc = C >> 5;
    int bc = blockIdx.x % nbc, br = blockIdx.x / nbc;
    int c0 = bc<<5, r0 = br<<5;
    int tx = threadIdx.x & 31, ty = threadIdx.x >> 5;
    #pragma unroll
    for (int i=0;i<4;i++){
        int r = ty + i*8;
        tile[r][tx] = f2bf(in[(size_t)(r0+r)*C + c0 + tx]);
    }
    __syncthreads();
    #pragma unroll
    for (int i=0;i<4;i++){
        int r = ty + i*8;
        out[(size_t)(c0+r)*R + r0 + tx] = tile[tx][r];
    }
}

// ---------- bf16 MFMA GEMM: C[M][N] = A[M][K] * Bt[N][K]^T ----------
template<bool OUT_BF16>
__global__ __launch_bounds__(256) void k_gemm_bt(const u16* __restrict__ A, const u16* __restrict__ Bt,
                                                 void* __restrict__ C, int M, int N, int K){
    __shared__ __align__(16) u16 As[128*64];
    __shared__ __align__(16) u16 Bs[128*64];
    const int tid  = threadIdx.x;
    const int bn   = blockIdx.x, bm = blockIdx.y;
    const int lane = tid & 63;
    const int wave = tid >> 6;
    const int wm = (wave >> 1) << 6;
    const int wn = (wave & 1) << 6;
    const int lr = lane & 15, lg = lane >> 4;
    f32x4 acc[4][4] = {};
    const size_t aRow0 = (size_t)bm*128;
    const size_t bRow0 = (size_t)bn*128;

    for (int kt = 0; kt < K; kt += 64){
        uint4 ra[4], rb[4];
        #pragma unroll
        for (int i=0;i<4;i++){
            int c = i*256 + tid;
            int row = c >> 3, ko = (c & 7) << 3;
            ra[i] = *(const uint4*)(A  + (aRow0 + row)*K + kt + ko);
            rb[i] = *(const uint4*)(Bt + (bRow0 + row)*K + kt + ko);
        }
        __syncthreads();   // previous tile's reads done
        #pragma unroll
        for (int i=0;i<4;i++){
            int c = i*256 + tid;
            *(uint4*)&As[(size_t)c<<3] = ra[i];
            *(uint4*)&Bs[(size_t)c<<3] = rb[i];
        }
        __syncthreads();
        #pragma unroll
        for (int kk=0; kk<2; kk++){
            bf16x8 af[4], bfv[4];
            #pragma unroll
            for (int i=0;i<4;i++){
                af[i]  = *(const bf16x8*)&As[((wm + i*16 + lr)<<6) + (kk<<5) + (lg<<3)];
                bfv[i] = *(const bf16x8*)&Bs[((wn + i*16 + lr)<<6) + (kk<<5) + (lg<<3)];
            }
            #pragma unroll
            for (int i=0;i<4;i++)
                #pragma unroll
                for (int j=0;j<4;j++)
                    acc[i][j] = __builtin_amdgcn_mfma_f32_16x16x32_bf16(af[i], bfv[j], acc[i][j], 0, 0, 0);
        }
    }
    #pragma unroll
    for (int i=0;i<4;i++)
        #pragma unroll
        for (int j=0;j<4;j++)
            #pragma unroll
            for (int r=0;r<4;r++){
                int row = bm*128 + wm + i*16 + lg*4 + r;
                int col = bn*128 + wn + j*16 + lr;
                if (OUT_BF16) ((u16*)C)[(size_t)row*N + col] = f2bf(acc[i][j][r]);
                else          ((float*)C)[(size_t)row*N + col] = acc[i][j][r];
            }
}

// ---------- ba = hidden @ W_ba ; beta = sigmoid, eg = exp(g) ----------
__global__ void k_ba(const float* __restrict__ hidden, const float* __restrict__ W_ba,
                     const float* __restrict__ dt_bias, const float* __restrict__ A_log,
                     float* __restrict__ beta, float* __restrict__ eg){
    int row = blockIdx.x*8 + (threadIdx.x>>5);
    int col = threadIdx.x & 31;
    const float* h = hidden + (size_t)row*HID;
    float s = 0.f;
    #pragma unroll 8
    for (int k=0;k<HID;k++) s = fmaf(h[k], W_ba[k*32+col], s);
    if (col < NH){
        beta[row*NH + col] = 1.f/(1.f+expf(-s));
    } else {
        int hh = col - NH;
        float x = s + dt_bias[hh];
        float sp = fmaxf(x,0.f) + log1pf(expf(-fabsf(x)));   // softplus, stable
        eg[row*NH + hh] = expf(-expf(A_log[hh])*sp);
    }
}

// ---------- causal depthwise conv (KW=4) + bias + SiLU ----------
__global__ void k_conv_silu(const u16* __restrict__ qkvz, const float* __restrict__ conv_w,
                            const float* __restrict__ conv_b, u16* __restrict__ mixed){
    long idx = (long)blockIdx.x*256 + threadIdx.x;
    int c = (int)(idx % CONV_CH);
    long bt = idx / CONV_CH;
    int t = (int)(bt % T_SEQ);
    const u16* base = qkvz + (size_t)bt*N_QKVZ + c;
    float4 w = *(const float4*)(conv_w + c*4);
    const float* wp = (const float*)&w;
    float acc = conv_b[c];
    #pragma unroll
    for (int wi=0; wi<3; wi++){
        int tt = t - 3 + wi;
        if (tt >= 0) acc = fmaf(bf2f(base[(ptrdiff_t)(wi-3)*N_QKVZ]), wp[wi], acc);
    }
    acc = fmaf(bf2f(base[0]), w.w, acc);
    float sv = acc / (1.f + __expf(-acc));
    mixed[(size_t)bt*CONV_CH + c] = f2bf(sv);
}

// ---------- l2-normalize q (and scale by DK^-1/2) and k, in place ----------
__global__ void k_qknorm(u16* __restrict__ mixed){
    int gw   = blockIdx.x*4 + (threadIdx.x>>6);
    int lane = threadIdx.x & 63;
    int bt = gw >> 5, r = gw & 31;        // r<16: q head r ; r>=16: k head r-16 (channel r*128 works for both)
    u16* p = mixed + (size_t)bt*CONV_CH + r*128 + lane*2;
    u32 u = *(u32*)p;
    float a = bflo(u), b = bfhi(u);
    float ss = a*a + b*b;
    #pragma unroll
    for (int m=1;m<64;m<<=1) ss += __shfl_xor(ss, m, 64);
    float sc = rsqrtf(ss + 1e-6f);
    if (r < 16) sc *= 0.08838834764831845f;   // DK^-0.5
    *(u32*)p = (u32)f2bf(a*sc) | ((u32)f2bf(b*sc)<<16);
}

// ---------- gated delta-rule scan, v-axis parallel ----------
// grid 512: blk = vc*32 + bh  (vc 0..15 -> 8 v each; bh = b*16+h). 128 threads:
// vloc = tid>>4 (0..7), kg = tid&15 owns k-range kg*8..kg*8+7 for column v.
__global__ __launch_bounds__(128) void k_scan(const u16* __restrict__ mixed,
        const float* __restrict__ beta, const float* __restrict__ eg, float* __restrict__ o){
    int blk = blockIdx.x;
    int bh = blk & 31, vc = blk >> 5;
    int b = bh >> 4, h = bh & 15;
    int tid = threadIdx.x;
    int vloc = tid >> 4, kg = tid & 15;
    int v = vc*8 + vloc;
    const u16* qb = mixed + (size_t)b*T_SEQ*CONV_CH + h*128 + kg*8;
    const u16* kb = qb + KD;
    const u16* vb = mixed + (size_t)b*T_SEQ*CONV_CH + 2*KD + h*128 + v;
    const float* egp = eg   + (size_t)b*T_SEQ*NH + h;
    const float* btp = beta + (size_t)b*T_SEQ*NH + h;
    float* op = o + ((size_t)b*T_SEQ*NH + h)*DKH + v;
    float S[8];
    #pragma unroll
    for (int j=0;j<8;j++) S[j] = 0.f;

    uint4 qc = *(const uint4*)qb;
    uint4 kc = *(const uint4*)kb;
    u16 vcur = *vb;
    float egc = egp[0], btc = btp[0];

    for (int t=0; t<T_SEQ; t++){
        uint4 qn = {0,0,0,0}, kn = {0,0,0,0}; u16 vn = 0; float egn = 0.f, btn = 0.f;
        if (t+1 < T_SEQ){                     // prefetch next step (hides HBM latency under compute)
            size_t off = (size_t)(t+1)*CONV_CH;
            qn = *(const uint4*)(qb + off);
            kn = *(const uint4*)(kb + off);
            vn = vb[off];
            egn = egp[(size_t)(t+1)*NH];
            btn = btp[(size_t)(t+1)*NH];
        }
        float kf[8], qf[8];
        kf[0]=bflo(kc.x); kf[1]=bfhi(kc.x); kf[2]=bflo(kc.y); kf[3]=bfhi(kc.y);
        kf[4]=bflo(kc.z); kf[5]=bfhi(kc.z); kf[6]=bflo(kc.w); kf[7]=bfhi(kc.w);
        qf[0]=bflo(qc.x); qf[1]=bfhi(qc.x); qf[2]=bflo(qc.y); qf[3]=bfhi(qc.y);
        qf[4]=bflo(qc.z); qf[5]=bfhi(qc.z); qf[6]=bflo(qc.w); qf[7]=bfhi(qc.w);
        float vf = bf2f(vcur);

        float kvp = 0.f;
        #pragma unroll
        for (int j=0;j<8;j++){ S[j] *= egc; kvp = fmaf(kf[j], S[j], kvp); }
        kvp += __shfl_xor(kvp,1,64); kvp += __shfl_xor(kvp,2,64);
        kvp += __shfl_xor(kvp,4,64); kvp += __shfl_xor(kvp,8,64);
        float delta = (vf - kvp)*btc;
        float oo = 0.f;
        #pragma unroll
        for (int j=0;j<8;j++){ S[j] = fmaf(kf[j], delta, S[j]); oo = fmaf(qf[j], S[j], oo); }
        oo += __shfl_xor(oo,1,64); oo += __shfl_xor(oo,2,64);
        oo += __shfl_xor(oo,4,64); oo += __shfl_xor(oo,8,64);
        if (kg == 0) op[(size_t)t*(NH*DKH)] = oo;
        qc = qn; kc = kn; vcur = vn; egc = egn; btc = btn;
    }
}

// ---------- x = RMSNorm(o * silu(z)) * norm_w, cast bf16 ----------
__global__ void k_gatenorm(const float* __restrict__ o, const u16* __restrict__ qkvz,
                           const float* __restrict__ norm_w, u16* __restrict__ x){
    int gw   = blockIdx.x*4 + (threadIdx.x>>6);
    int lane = threadIdx.x & 63;
    int bt = gw >> 4, h = gw & 15;
    const float* opr = o + ((size_t)bt*NH + h)*DKH + lane*2;
    const u16* zp = qkvz + (size_t)bt*N_QKVZ + (2*KD+VD) + h*DKH + lane*2;
    float o0 = opr[0], o1 = opr[1];
    u32 zu = *(const u32*)zp;
    float z0 = bflo(zu), z1 = bfhi(zu);
    float x0 = o0 * (z0/(1.f+__expf(-z0)));
    float x1 = o1 * (z1/(1.f+__expf(-z1)));
    float ss = x0*x0 + x1*x1;
    #pragma unroll
    for (int m=1;m<64;m<<=1) ss += __shfl_xor(ss, m, 64);
    float sc = rsqrtf(ss*(1.f/128.f) + 1e-6f);
    x0 *= sc*norm_w[lane*2]; x1 *= sc*norm_w[lane*2+1];
    ((u32*)x)[(size_t)bt*(VD/2) + h*(DKH/2) + lane] = (u32)f2bf(x0) | ((u32)f2bf(x1)<<16);
}

extern "C" void kernel_launch(void* const* d_in, const int* in_sizes, int n_in,
                              void* d_out, int out_size, void* d_ws, size_t ws_size,
                              hipStream_t stream){
    (void)in_sizes; (void)n_in; (void)out_size; (void)ws_size;
    const float* hidden = (const float*)d_in[0];
    const float* W_qkvz = (const float*)d_in[1];
    const float* W_ba   = (const float*)d_in[2];
    const float* conv_w = (const float*)d_in[3];
    const float* conv_b = (const float*)d_in[4];
    const float* dt_bias= (const float*)d_in[5];
    const float* A_log  = (const float*)d_in[6];
    const float* norm_w = (const float*)d_in[7];
    const float* W_out  = (const float*)d_in[8];
    float* out = (float*)d_out;

    char* ws = (char*)d_ws;
    size_t off = 0;
    auto alloc = [&](size_t bytes)->char*{ char* p = ws + off; off += (bytes + 255) & ~(size_t)255; return p; };
    u16*   h_bf  = (u16*)  alloc((size_t)MROWS*HID*2);       // 50.3 MB
    u16*   WqT   = (u16*)  alloc((size_t)N_QKVZ*HID*2);      // 50.3 MB
    u16*   WoT   = (u16*)  alloc((size_t)HID*VD*2);          // 12.6 MB
    u16*   qkvz  = (u16*)  alloc((size_t)MROWS*N_QKVZ*2);    // 134 MB
    u16*   mixed = (u16*)  alloc((size_t)MROWS*CONV_CH*2);   // 100.7 MB
    float* beta_b= (float*)alloc((size_t)MROWS*NH*4);
    float* eg_b  = (float*)alloc((size_t)MROWS*NH*4);
    // overlay: h_bf & WqT are dead after GEMM1 -> reuse for o (67.1 MB) and x (33.6 MB)
    float* o_b = (float*)h_bf;
    u16*   x_b = (u16*)((char*)h_bf + (size_t)MROWS*VD*4);

    k_cast<<<2048,256,0,stream>>>(hidden, h_bf, MROWS*HID/4);
    k_transpose_cast<<<(HID/32)*(N_QKVZ/32),256,0,stream>>>(W_qkvz, WqT, HID, N_QKVZ);
    k_transpose_cast<<<(VD/32)*(HID/32),256,0,stream>>>(W_out, WoT, VD, HID);
    k_gemm_bt<true><<<dim3(N_QKVZ/128, MROWS/128),256,0,stream>>>(h_bf, WqT, qkvz, MROWS, N_QKVZ, HID);
    k_ba<<<MROWS/8,256,0,stream>>>(hidden, W_ba, dt_bias, A_log, beta_b, eg_b);
    k_conv_silu<<<(long)MROWS*CONV_CH/256,256,0,stream>>>(qkvz, conv_w, conv_b, mixed);
    k_qknorm<<<MROWS*32/4,256,0,stream>>>(mixed);
    k_scan<<<512,128,0,stream>>>(mixed, beta_b, eg_b, o_b);
    k_gatenorm<<<MROWS*NH/4,256,0,stream>>>(o_b, qkvz, norm_w, x_b);
    k_gemm_bt<false><<<dim3(HID/128, MROWS/128),256,0,stream>>>(x_b, WoT, out, MROWS, HID, VD);
}

// Round 2
// 2597.490 us; speedup vs baseline: 2.0907x; 2.0907x over previous
//
#include <hip/hip_runtime.h>
#include <cstdint>
#include <cstddef>

#define T_SEQ 4096
#define HID 3072
#define NH 16
#define DKH 128
#define KD 2048
#define VD 2048
#define N_QKVZ 8192
#define CONV_CH 6144
#define MROWS 8192  // B*T

typedef unsigned short u16;
typedef unsigned int u32;

typedef __attribute__((ext_vector_type(8))) short bf16x8;
typedef __attribute__((ext_vector_type(4))) float f32x4;

__device__ __forceinline__ float bf2f(u16 u){ u32 t=((u32)u)<<16; float f; __builtin_memcpy(&f,&t,4); return f; }
__device__ __forceinline__ float bflo(u32 u){ u32 t=u<<16; float f; __builtin_memcpy(&f,&t,4); return f; }
__device__ __forceinline__ float bfhi(u32 u){ u32 t=u&0xffff0000u; float f; __builtin_memcpy(&f,&t,4); return f; }
__device__ __forceinline__ u16 f2bf(float f){ u32 i; __builtin_memcpy(&i,&f,4); return (u16)((i + 0x7fffu + ((i>>16)&1u))>>16); }

// ---- async global->LDS, 16B per lane; LDS dest = uniform base + lane*16 ----
__device__ __forceinline__ void gl_lds16(const u16* g, u16* l){
    __builtin_amdgcn_global_load_lds(
        (const __attribute__((address_space(1))) void*)g,
        (__attribute__((address_space(3))) void*)l, 16, 0, 0);
}

// ---- 16-lane sum reduction entirely on the VALU pipe via DPP ----
// xor1 = quad_perm[1,0,3,2]=0xB1 ; xor2 = quad_perm[2,3,0,1]=0x4E ;
// xor7 = row_half_mirror 0x141 ; xor15 = row_mirror 0x140 (rows = 16 lanes)
template<int C>
__device__ __forceinline__ float dpp_xadd(float x){
    int xi; __builtin_memcpy(&xi,&x,4);
    int yi = __builtin_amdgcn_update_dpp(0, xi, C, 0xF, 0xF, true);
    float y; __builtin_memcpy(&y,&yi,4);
    return x + y;
}
__device__ __forceinline__ float red16(float x){
    x = dpp_xadd<0xB1>(x);
    x = dpp_xadd<0x4E>(x);
    x = dpp_xadd<0x141>(x);
    x = dpp_xadd<0x140>(x);
    return x;
}

// ---------- cast f32 -> bf16 (flat) ----------
__global__ void k_cast(const float* __restrict__ in, u16* __restrict__ out, int n4){
    int stride = gridDim.x*blockDim.x;
    for (int i = blockIdx.x*blockDim.x + threadIdx.x; i < n4; i += stride){
        float4 v = ((const float4*)in)[i];
        u32 lo = (u32)f2bf(v.x) | ((u32)f2bf(v.y)<<16);
        u32 hi = (u32)f2bf(v.z) | ((u32)f2bf(v.w)<<16);
        ((uint2*)out)[i] = make_uint2(lo,hi);
    }
}

// ---------- transpose + cast: in[R][C] f32 -> out[C][R] bf16 ----------
__global__ void k_transpose_cast(const float* __restrict__ in, u16* __restrict__ out, int R, int C){
    __shared__ u16 tile[32][33];
    int nbc = C >> 5;
    int bc = blockIdx.x % nbc, br = blockIdx.x / nbc;
    int c0 = bc<<5, r0 = br<<5;
    int tx = threadIdx.x & 31, ty = threadIdx.x >> 5;
    #pragma unroll
    for (int i=0;i<4;i++){
        int r = ty + i*8;
        tile[r][tx] = f2bf(in[(size_t)(r0+r)*C + c0 + tx]);
    }
    __syncthreads();
    #pragma unroll
    for (int i=0;i<4;i++){
        int r = ty + i*8;
        out[(size_t)(c0+r)*R + r0 + tx] = tile[tx][r];
    }
}

// ---------- bf16 MFMA GEMM (m97 structure): C[M][N] = A[M][K] * Bt[N][K]^T ----------
template<bool OUT_BF16>
__global__ __launch_bounds__(256) void k_gemm_bt(const u16* __restrict__ A, const u16* __restrict__ Bt,
                                                 void* __restrict__ C, int M, int N, int K){
    __shared__ __align__(16) u16 As[128*64];
    __shared__ __align__(16) u16 Bs[128*64];
    const int tid  = threadIdx.x;
    const int bn   = blockIdx.x, bm = blockIdx.y;
    const int lane = tid & 63;
    const int wave = tid >> 6;
    const int wm = (wave >> 1) << 6;
    const int wn = (wave & 1) << 6;
    const int lr = lane & 15, lg = lane >> 4;
    f32x4 acc[4][4] = {};
    const size_t aRow0 = (size_t)bm*128;
    const size_t bRow0 = (size_t)bn*128;
    // staging: wave w brings A rows 32w..32w+31 and B rows 32w..32w+31 (4 chunks of 8 rows each)
    const int srow = wave*32 + (lane>>3);      // row within 128-tile for this lane (chunk i adds 8i)
    const int scol = (lane&7)*8;               // u16 col offset within 64-wide K-slab

    for (int kt = 0; kt < K; kt += 64){
        const u16* ga = A  + (aRow0 + srow)*K + kt + scol;
        const u16* gb = Bt + (bRow0 + srow)*K + kt + scol;
        u16* la = As + wave*32*64;
        u16* lb = Bs + wave*32*64;
        #pragma unroll
        for (int i=0;i<4;i++){
            gl_lds16(ga + (size_t)i*8*K, la + i*512);
            gl_lds16(gb + (size_t)i*8*K, lb + i*512);
        }
        __syncthreads();   // drains vmcnt: LDS tile ready
        #pragma unroll
        for (int kk=0; kk<2; kk++){
            bf16x8 af[4], bfv[4];
            #pragma unroll
            for (int i=0;i<4;i++){
                af[i]  = *(const bf16x8*)&As[((wm + i*16 + lr)<<6) + (kk<<5) + (lg<<3)];
                bfv[i] = *(const bf16x8*)&Bs[((wn + i*16 + lr)<<6) + (kk<<5) + (lg<<3)];
            }
            #pragma unroll
            for (int i=0;i<4;i++)
                #pragma unroll
                for (int j=0;j<4;j++)
                    acc[i][j] = __builtin_amdgcn_mfma_f32_16x16x32_bf16(af[i], bfv[j], acc[i][j], 0, 0, 0);
        }
        __syncthreads();   // compute done: LDS free for next tile
    }
    #pragma unroll
    for (int i=0;i<4;i++)
        #pragma unroll
        for (int j=0;j<4;j++)
            #pragma unroll
            for (int r=0;r<4;r++){
                int row = bm*128 + wm + i*16 + lg*4 + r;
                int col = bn*128 + wn + j*16 + lr;
                if (OUT_BF16) ((u16*)C)[(size_t)row*N + col] = f2bf(acc[i][j][r]);
                else          ((float*)C)[(size_t)row*N + col] = acc[i][j][r];
            }
}

// ---------- ba = hidden @ W_ba ; be[].x = sigmoid(b), be[].y = exp(g) ----------
__global__ void k_ba(const float* __restrict__ hidden, const float* __restrict__ W_ba,
                     const float* __restrict__ dt_bias, const float* __restrict__ A_log,
                     float2* __restrict__ be){
    int row = blockIdx.x*8 + (threadIdx.x>>5);
    int col = threadIdx.x & 31;
    const float* h = hidden + (size_t)row*HID;
    float s = 0.f;
    #pragma unroll 8
    for (int k=0;k<HID;k++) s = fmaf(h[k], W_ba[k*32+col], s);
    if (col < NH){
        be[(size_t)row*NH + col].x = 1.f/(1.f+expf(-s));
    } else {
        int hh = col - NH;
        float x = s + dt_bias[hh];
        float sp = fmaxf(x,0.f) + log1pf(expf(-fabsf(x)));   // softplus, stable
        be[(size_t)row*NH + hh].y = expf(-expf(A_log[hh])*sp);
    }
}

// ---------- causal depthwise conv (KW=4) + bias + SiLU ----------
__global__ void k_conv_silu(const u16* __restrict__ qkvz, const float* __restrict__ conv_w,
                            const float* __restrict__ conv_b, u16* __restrict__ mixed){
    long idx = (long)blockIdx.x*256 + threadIdx.x;
    int c = (int)(idx % CONV_CH);
    long bt = idx / CONV_CH;
    int t = (int)(bt % T_SEQ);
    const u16* base = qkvz + (size_t)bt*N_QKVZ + c;
    float4 w = *(const float4*)(conv_w + c*4);
    const float* wp = (const float*)&w;
    float acc = conv_b[c];
    #pragma unroll
    for (int wi=0; wi<3; wi++){
        int tt = t - 3 + wi;
        if (tt >= 0) acc = fmaf(bf2f(base[(ptrdiff_t)(wi-3)*N_QKVZ]), wp[wi], acc);
    }
    acc = fmaf(bf2f(base[0]), w.w, acc);
    float sv = acc / (1.f + __expf(-acc));
    mixed[(size_t)bt*CONV_CH + c] = f2bf(sv);
}

// ---------- l2-normalize q (and scale by DK^-1/2) and k, in place ----------
__global__ void k_qknorm(u16* __restrict__ mixed){
    int gw   = blockIdx.x*4 + (threadIdx.x>>6);
    int lane = threadIdx.x & 63;
    int bt = gw >> 5, r = gw & 31;
    u16* p = mixed + (size_t)bt*CONV_CH + r*128 + lane*2;
    u32 u = *(u32*)p;
    float a = bflo(u), b = bfhi(u);
    float ss = a*a + b*b;
    #pragma unroll
    for (int m=1;m<64;m<<=1) ss += __shfl_xor(ss, m, 64);
    float sc = rsqrtf(ss + 1e-6f);
    if (r < 16) sc *= 0.08838834764831845f;   // DK^-0.5
    *(u32*)p = (u32)f2bf(a*sc) | ((u32)f2bf(b*sc)<<16);
}

// ---------- gated delta-rule scan, v-axis parallel, depth-8 prefetch + DPP reduce ----------
// grid 512: blk = vc*32 + bh. 128 threads: vloc = tid>>4 (8 v per block), kg = tid&15 (8 k each).
__global__ __launch_bounds__(128) void k_scan(const u16* __restrict__ mixed,
        const float2* __restrict__ be, float* __restrict__ o){
    int blk = blockIdx.x;
    int bh = blk & 31, vc = blk >> 5;
    int b = bh >> 4, h = bh & 15;
    int tid = threadIdx.x;
    int vloc = tid >> 4, kg = tid & 15;
    int v = vc*8 + vloc;
    const u16* qb = mixed + (size_t)b*T_SEQ*CONV_CH + h*128 + kg*8;
    const u16* kb = qb + KD;
    const u16* vb = mixed + (size_t)b*T_SEQ*CONV_CH + 2*KD + h*128 + v;
    const float2* bep = be + (size_t)b*T_SEQ*NH + h;
    float* op = o + ((size_t)b*T_SEQ*NH + h)*DKH + v;
    float S[8];
    #pragma unroll
    for (int j=0;j<8;j++) S[j] = 0.f;

    uint4 q0,k0,q1,k1,q2,k2,q3,k3,q4,k4,q5,k5,q6,k6,q7,k7;
    u16 v0,v1,v2,v3,v4,v5,v6,v7;
    float2 be0,be1,be2,be3,be4,be5,be6,be7;

#define PRELOAD(s) { size_t off=(size_t)(s)*CONV_CH; \
    q##s = *(const uint4*)(qb+off); k##s = *(const uint4*)(kb+off); \
    v##s = vb[off]; be##s = bep[(size_t)(s)*NH]; }
    PRELOAD(0) PRELOAD(1) PRELOAD(2) PRELOAD(3)
    PRELOAD(4) PRELOAD(5) PRELOAD(6) PRELOAD(7)
#undef PRELOAD

#define STEP(s, tt) { \
    float kf[8], qf[8]; \
    kf[0]=bflo(k##s.x); kf[1]=bfhi(k##s.x); kf[2]=bflo(k##s.y); kf[3]=bfhi(k##s.y); \
    kf[4]=bflo(k##s.z); kf[5]=bfhi(k##s.z); kf[6]=bflo(k##s.w); kf[7]=bfhi(k##s.w); \
    qf[0]=bflo(q##s.x); qf[1]=bfhi(q##s.x); qf[2]=bflo(q##s.y); qf[3]=bfhi(q##s.y); \
    qf[4]=bflo(q##s.z); qf[5]=bfhi(q##s.z); qf[6]=bflo(q##s.w); qf[7]=bfhi(q##s.w); \
    float vf = bf2f(v##s); \
    float egc = be##s.y, btc = be##s.x; \
    _Pragma("unroll") \
    for (int j=0;j<8;j++) S[j] *= egc; \
    float kvp = ((kf[0]*S[0]+kf[1]*S[1]) + (kf[2]*S[2]+kf[3]*S[3])) \
              + ((kf[4]*S[4]+kf[5]*S[5]) + (kf[6]*S[6]+kf[7]*S[7])); \
    kvp = red16(kvp); \
    float delta = (vf - kvp)*btc; \
    _Pragma("unroll") \
    for (int j=0;j<8;j++) S[j] = fmaf(kf[j], delta, S[j]); \
    float oo = ((qf[0]*S[0]+qf[1]*S[1]) + (qf[2]*S[2]+qf[3]*S[3])) \
             + ((qf[4]*S[4]+qf[5]*S[5]) + (qf[6]*S[6]+qf[7]*S[7])); \
    oo = red16(oo); \
    if (kg == 0) op[(size_t)(tt)*(NH*DKH)] = oo; \
    if ((tt)+8 < T_SEQ) { size_t off=(size_t)((tt)+8)*CONV_CH; \
        q##s = *(const uint4*)(qb+off); k##s = *(const uint4*)(kb+off); \
        v##s = vb[off]; be##s = bep[(size_t)((tt)+8)*NH]; } }

    for (int t=0; t<T_SEQ; t+=8){
        STEP(0,t)   STEP(1,t+1) STEP(2,t+2) STEP(3,t+3)
        STEP(4,t+4) STEP(5,t+5) STEP(6,t+6) STEP(7,t+7)
    }
#undef STEP
}

// ---------- x = RMSNorm(o * silu(z)) * norm_w, cast bf16 ----------
__global__ void k_gatenorm(const float* __restrict__ o, const u16* __restrict__ qkvz,
                           const float* __restrict__ norm_w, u16* __restrict__ x){
    int gw   = blockIdx.x*4 + (threadIdx.x>>6);
    int lane = threadIdx.x & 63;
    int bt = gw >> 4, h = gw & 15;
    const float* opr = o + ((size_t)bt*NH + h)*DKH + lane*2;
    const u16* zp = qkvz + (size_t)bt*N_QKVZ + (2*KD+VD) + h*DKH + lane*2;
    float o0 = opr[0], o1 = opr[1];
    u32 zu = *(const u32*)zp;
    float z0 = bflo(zu), z1 = bfhi(zu);
    float x0 = o0 * (z0/(1.f+__expf(-z0)));
    float x1 = o1 * (z1/(1.f+__expf(-z1)));
    float ss = x0*x0 + x1*x1;
    #pragma unroll
    for (int m=1;m<64;m<<=1) ss += __shfl_xor(ss, m, 64);
    float sc = rsqrtf(ss*(1.f/128.f) + 1e-6f);
    x0 *= sc*norm_w[lane*2]; x1 *= sc*norm_w[lane*2+1];
    ((u32*)x)[(size_t)bt*(VD/2) + h*(DKH/2) + lane] = (u32)f2bf(x0) | ((u32)f2bf(x1)<<16);
}

extern "C" void kernel_launch(void* const* d_in, const int* in_sizes, int n_in,
                              void* d_out, int out_size, void* d_ws, size_t ws_size,
                              hipStream_t stream){
    (void)in_sizes; (void)n_in; (void)out_size; (void)ws_size;
    const float* hidden = (const float*)d_in[0];
    const float* W_qkvz = (const float*)d_in[1];
    const float* W_ba   = (const float*)d_in[2];
    const float* conv_w = (const float*)d_in[3];
    const float* conv_b = (const float*)d_in[4];
    const float* dt_bias= (const float*)d_in[5];
    const float* A_log  = (const float*)d_in[6];
    const float* norm_w = (const float*)d_in[7];
    const float* W_out  = (const float*)d_in[8];
    float* out = (float*)d_out;

    char* ws = (char*)d_ws;
    size_t off = 0;
    auto alloc = [&](size_t bytes)->char*{ char* p = ws + off; off += (bytes + 255) & ~(size_t)255; return p; };
    u16*   h_bf  = (u16*)  alloc((size_t)MROWS*HID*2);       // 50.3 MB
    u16*   WqT   = (u16*)  alloc((size_t)N_QKVZ*HID*2);      // 50.3 MB
    u16*   WoT   = (u16*)  alloc((size_t)HID*VD*2);          // 12.6 MB
    u16*   qkvz  = (u16*)  alloc((size_t)MROWS*N_QKVZ*2);    // 134 MB
    u16*   mixed = (u16*)  alloc((size_t)MROWS*CONV_CH*2);   // 100.7 MB
    float2* be_b = (float2*)alloc((size_t)MROWS*NH*8);
    // overlay: h_bf & WqT dead after GEMM1 -> reuse for o (67.1 MB) and x (33.6 MB)
    float* o_b = (float*)h_bf;
    u16*   x_b = (u16*)((char*)h_bf + (size_t)MROWS*VD*4);

    k_cast<<<2048,256,0,stream>>>(hidden, h_bf, MROWS*HID/4);
    k_transpose_cast<<<(HID/32)*(N_QKVZ/32),256,0,stream>>>(W_qkvz, WqT, HID, N_QKVZ);
    k_transpose_cast<<<(VD/32)*(HID/32),256,0,stream>>>(W_out, WoT, VD, HID);
    k_gemm_bt<true><<<dim3(N_QKVZ/128, MROWS/128),256,0,stream>>>(h_bf, WqT, qkvz, MROWS, N_QKVZ, HID);
    k_ba<<<MROWS/8,256,0,stream>>>(hidden, W_ba, dt_bias, A_log, be_b);
    k_conv_silu<<<(long)MROWS*CONV_CH/256,256,0,stream>>>(qkvz, conv_w, conv_b, mixed);
    k_qknorm<<<MROWS*32/4,256,0,stream>>>(mixed);
    k_scan<<<512,128,0,stream>>>(mixed, be_b, o_b);
    k_gatenorm<<<MROWS*NH/4,256,0,stream>>>(o_b, qkvz, norm_w, x_b);
    k_gemm_bt<false><<<dim3(HID/128, MROWS/128),256,0,stream>>>(x_b, WoT, out, MROWS, HID, VD);
}

// Round 4
// 1691.061 us; speedup vs baseline: 3.2114x; 1.5360x over previous
//
#include <hip/hip_runtime.h>
#include <cstdint>
#include <cstddef>

#define T_SEQ 4096
#define HID 3072
#define NH 16
#define DKH 128
#define KD 2048
#define VD 2048
#define N_QKVZ 8192
#define CONV_CH 6144
#define MROWS 8192  // B*T

typedef unsigned short u16;
typedef unsigned int u32;

typedef __attribute__((ext_vector_type(8))) short bf16x8;
typedef __attribute__((ext_vector_type(4))) float f32x4;

__device__ __forceinline__ float bf2f(u16 u){ u32 t=((u32)u)<<16; float f; __builtin_memcpy(&f,&t,4); return f; }
__device__ __forceinline__ float bflo(u32 u){ u32 t=u<<16; float f; __builtin_memcpy(&f,&t,4); return f; }
__device__ __forceinline__ float bfhi(u32 u){ u32 t=u&0xffff0000u; float f; __builtin_memcpy(&f,&t,4); return f; }
__device__ __forceinline__ u16 f2bf(float f){ u32 i; __builtin_memcpy(&i,&f,4); return (u16)((i + 0x7fffu + ((i>>16)&1u))>>16); }

__device__ __forceinline__ void gl_lds16(const u16* g, u16* l){
    __builtin_amdgcn_global_load_lds(
        (const __attribute__((address_space(1))) void*)g,
        (__attribute__((address_space(3))) void*)l, 16, 0, 0);
}

__device__ __forceinline__ bf16x8 frag(const u16* p, int row, int stride, int k0){
    return *(const bf16x8*)(p + (size_t)row*stride + k0);
}

// ---------- cast f32 -> bf16 (flat) ----------
__global__ void k_cast(const float* __restrict__ in, u16* __restrict__ out, int n4){
    int stride = gridDim.x*blockDim.x;
    for (int i = blockIdx.x*blockDim.x + threadIdx.x; i < n4; i += stride){
        float4 v = ((const float4*)in)[i];
        u32 lo = (u32)f2bf(v.x) | ((u32)f2bf(v.y)<<16);
        u32 hi = (u32)f2bf(v.z) | ((u32)f2bf(v.w)<<16);
        ((uint2*)out)[i] = make_uint2(lo,hi);
    }
}

// ---------- transpose + cast: in[R][C] f32 -> out[C][R] bf16 ----------
__global__ void k_transpose_cast(const float* __restrict__ in, u16* __restrict__ out, int R, int C){
    __shared__ u16 tile[32][33];
    int nbc = C >> 5;
    int bc = blockIdx.x % nbc, br = blockIdx.x / nbc;
    int c0 = bc<<5, r0 = br<<5;
    int tx = threadIdx.x & 31, ty = threadIdx.x >> 5;
    #pragma unroll
    for (int i=0;i<4;i++){
        int r = ty + i*8;
        tile[r][tx] = f2bf(in[(size_t)(r0+r)*C + c0 + tx]);
    }
    __syncthreads();
    #pragma unroll
    for (int i=0;i<4;i++){
        int r = ty + i*8;
        out[(size_t)(c0+r)*R + r0 + tx] = tile[tx][r];
    }
}

// ---------- bf16 MFMA GEMM: C = A[M][K] * Bt[N][K]^T, column-split output ----------
template<bool OUT_BF16>
__global__ __launch_bounds__(256) void k_gemm_bt(const u16* __restrict__ A, const u16* __restrict__ Bt,
                                                 void* __restrict__ C1, void* __restrict__ C2,
                                                 int M, int N, int K, int csplit, int ld1, int ld2){
    __shared__ __align__(16) u16 As[128*64];
    __shared__ __align__(16) u16 Bs[128*64];
    const int tid  = threadIdx.x;
    const int bn   = blockIdx.x, bm = blockIdx.y;
    const int lane = tid & 63;
    const int wave = tid >> 6;
    const int wm = (wave >> 1) << 6;
    const int wn = (wave & 1) << 6;
    const int lr = lane & 15, lg = lane >> 4;
    f32x4 acc[4][4] = {};
    const size_t aRow0 = (size_t)bm*128;
    const size_t bRow0 = (size_t)bn*128;
    const int srow = wave*32 + (lane>>3);
    const int scol = (lane&7)*8;

    for (int kt = 0; kt < K; kt += 64){
        const u16* ga = A  + (aRow0 + srow)*K + kt + scol;
        const u16* gb = Bt + (bRow0 + srow)*K + kt + scol;
        u16* la = As + wave*32*64;
        u16* lb = Bs + wave*32*64;
        #pragma unroll
        for (int i=0;i<4;i++){
            gl_lds16(ga + (size_t)i*8*K, la + i*512);
            gl_lds16(gb + (size_t)i*8*K, lb + i*512);
        }
        __syncthreads();
        #pragma unroll
        for (int kk=0; kk<2; kk++){
            bf16x8 af[4], bfv[4];
            #pragma unroll
            for (int i=0;i<4;i++){
                af[i]  = *(const bf16x8*)&As[((wm + i*16 + lr)<<6) + (kk<<5) + (lg<<3)];
                bfv[i] = *(const bf16x8*)&Bs[((wn + i*16 + lr)<<6) + (kk<<5) + (lg<<3)];
            }
            #pragma unroll
            for (int i=0;i<4;i++)
                #pragma unroll
                for (int j=0;j<4;j++)
                    acc[i][j] = __builtin_amdgcn_mfma_f32_16x16x32_bf16(af[i], bfv[j], acc[i][j], 0, 0, 0);
        }
        __syncthreads();
    }
    #pragma unroll
    for (int i=0;i<4;i++)
        #pragma unroll
        for (int j=0;j<4;j++)
            #pragma unroll
            for (int r=0;r<4;r++){
                int row = bm*128 + wm + i*16 + lg*4 + r;
                int col = bn*128 + wn + j*16 + lr;
                if (OUT_BF16){
                    if (col < csplit) ((u16*)C1)[(size_t)row*ld1 + col] = f2bf(acc[i][j][r]);
                    else              ((u16*)C2)[(size_t)row*ld2 + (col-csplit)] = f2bf(acc[i][j][r]);
                } else {
                    ((float*)C1)[(size_t)row*ld1 + col] = acc[i][j][r];
                }
            }
}

// ---------- ba = hidden @ W_ba ; be[].x = sigmoid(b), be[].y = g (log-decay) ----------
__global__ void k_ba(const float* __restrict__ hidden, const float* __restrict__ W_ba,
                     const float* __restrict__ dt_bias, const float* __restrict__ A_log,
                     float2* __restrict__ be){
    int row = blockIdx.x*8 + (threadIdx.x>>5);
    int col = threadIdx.x & 31;
    const float* h = hidden + (size_t)row*HID;
    float s = 0.f;
    #pragma unroll 8
    for (int k=0;k<HID;k++) s = fmaf(h[k], W_ba[k*32+col], s);
    if (col < NH){
        be[(size_t)row*NH + col].x = 1.f/(1.f+expf(-s));
    } else {
        int hh = col - NH;
        float x = s + dt_bias[hh];
        float sp = fmaxf(x,0.f) + log1pf(expf(-fabsf(x)));   // softplus, stable
        be[(size_t)row*NH + hh].y = -expf(A_log[hh])*sp;     // g (not exponentiated)
    }
}

// ---------- causal depthwise conv (KW=4) + bias + SiLU ; input [MROWS][6144] ----------
__global__ void k_conv_silu(const u16* __restrict__ qkv, const float* __restrict__ conv_w,
                            const float* __restrict__ conv_b, u16* __restrict__ mixed){
    long idx = (long)blockIdx.x*256 + threadIdx.x;
    int c = (int)(idx % CONV_CH);
    long bt = idx / CONV_CH;
    int t = (int)(bt % T_SEQ);
    const u16* base = qkv + (size_t)bt*CONV_CH + c;
    float4 w = *(const float4*)(conv_w + c*4);
    const float* wp = (const float*)&w;
    float acc = conv_b[c];
    #pragma unroll
    for (int wi=0; wi<3; wi++){
        int tt = t - 3 + wi;
        if (tt >= 0) acc = fmaf(bf2f(base[(ptrdiff_t)(wi-3)*CONV_CH]), wp[wi], acc);
    }
    acc = fmaf(bf2f(base[0]), w.w, acc);
    float sv = acc / (1.f + __expf(-acc));
    mixed[(size_t)bt*CONV_CH + c] = f2bf(sv);
}

// ---------- l2-normalize q (and scale by DK^-1/2) and k, in place ----------
__global__ void k_qknorm(u16* __restrict__ mixed){
    int gw   = blockIdx.x*4 + (threadIdx.x>>6);
    int lane = threadIdx.x & 63;
    int bt = gw >> 5, r = gw & 31;
    u16* p = mixed + (size_t)bt*CONV_CH + r*128 + lane*2;
    u32 u = *(u32*)p;
    float a = bflo(u), b = bfhi(u);
    float ss = a*a + b*b;
    #pragma unroll
    for (int m=1;m<64;m<<=1) ss += __shfl_xor(ss, m, 64);
    float sc = rsqrtf(ss + 1e-6f);
    if (r < 16) sc *= 0.08838834764831845f;   // DK^-0.5
    *(u32*)p = (u32)f2bf(a*sc) | ((u32)f2bf(b*sc)<<16);
}

// ================= chunked delta rule =================
__global__ __launch_bounds__(512) void k_prep(const u16* __restrict__ mixed,
        const float2* __restrict__ be, u16* __restrict__ Wcg, u16* __restrict__ Ucg,
        float* __restrict__ barr){
    __shared__ __align__(16) u16 Ks[64*128];
    __shared__ __align__(16) u16 Vs[64*128];
    __shared__ float Am[64*64];
    __shared__ __align__(16) float RHS[64*256];
    __shared__ float bv[64], betav[64], lamv[64];
    const int tid = threadIdx.x;
    const int lane = tid & 63, wave = tid >> 6;
    const int lr = lane & 15, lg = lane >> 4;
    const int chunk = blockIdx.x;
    const int ci = chunk & 63, bh = chunk >> 6, b = bh >> 4, h = bh & 15;
    const size_t rowbase = (size_t)b*T_SEQ + ci*64;

    const u16* kg = mixed + rowbase*CONV_CH + KD + h*128;
    const u16* vg = mixed + rowbase*CONV_CH + 2*KD + h*128;
    #pragma unroll
    for (int pass=0; pass<2; pass++){
        int row = (tid>>4) + pass*32;
        int co = (tid&15)*8;
        gl_lds16(kg + (size_t)row*CONV_CH + co, Ks + row*128 + co);
        gl_lds16(vg + (size_t)row*CONV_CH + co, Vs + row*128 + co);
    }
    if (tid < 64){
        float2 bg = be[(rowbase + tid)*NH + h];
        float acc = bg.y;
        #pragma unroll
        for (int m=1;m<64;m<<=1){ float u = __shfl_up(acc, m, 64); if (tid >= m) acc += u; }
        bv[tid] = acc; betav[tid] = bg.x; lamv[tid] = __expf(acc);
        barr[(size_t)chunk*64 + tid] = acc;
    }
    __syncthreads();
    #pragma unroll
    for (int i=0;i<2;i++){
        int tile = wave*2 + i;
        int tm = tile>>2, tn = tile&3;
        f32x4 acc = {};
        #pragma unroll
        for (int kk=0;kk<4;kk++)
            acc = __builtin_amdgcn_mfma_f32_16x16x32_bf16(
                frag(Ks, tm*16+lr, 128, kk*32+lg*8),
                frag(Ks, tn*16+lr, 128, kk*32+lg*8), acc, 0,0,0);
        #pragma unroll
        for (int r=0;r<4;r++){
            int t = tm*16 + lg*4 + r, s = tn*16 + lr;
            Am[t*64+s] = (t>s) ? betav[t]*__expf(bv[t]-bv[s])*acc[r] : 0.f;
        }
    }
    __syncthreads();
    for (int i=tid; i<64*256; i+=512){
        int r = i>>8, j = i&255;
        RHS[i] = (j<128) ? betav[r]*lamv[r]*bf2f(Ks[r*128+j])
                         : betav[r]*bf2f(Vs[r*128 + (j-128)]);
    }
    __syncthreads();
    for (int blk=0; blk<8; blk++){
        int base = blk*8;
        if (base){
            int r = base + (tid>>6);
            int j0 = (tid&63)*4;
            float4 x = *(float4*)&RHS[r*256 + j0];
            for (int s=0; s<base; s++){
                float a = Am[r*64+s];
                float4 y = *(float4*)&RHS[s*256 + j0];
                x.x = fmaf(-a, y.x, x.x); x.y = fmaf(-a, y.y, x.y);
                x.z = fmaf(-a, y.z, x.z); x.w = fmaf(-a, y.w, x.w);
            }
            *(float4*)&RHS[r*256 + j0] = x;
        }
        __syncthreads();
        if (tid < 256){
            float x[8];
            #pragma unroll
            for (int i=0;i<8;i++) x[i] = RHS[(base+i)*256 + tid];
            #pragma unroll
            for (int r=1;r<8;r++)
                #pragma unroll
                for (int s=0;s<r;s++)
                    x[r] = fmaf(-Am[(base+r)*64 + base+s], x[s], x[r]);
            #pragma unroll
            for (int i=1;i<8;i++) RHS[(base+i)*256 + tid] = x[i];
        }
        __syncthreads();
    }
    for (int i=tid; i<8192; i+=512){
        int r = i>>7, c = i&127;
        Wcg[(size_t)chunk*8192 + i] = f2bf(RHS[r*256 + c]);
        Ucg[(size_t)chunk*8192 + i] = f2bf(RHS[r*256 + 128 + c]);
    }
}

// ---------- sequential chunk recurrence + fused o1 = diag(e^b) Q @ S0 ----------
__global__ __launch_bounds__(256) void k_seq(const u16* __restrict__ mixed,
        const u16* __restrict__ Wcg, const u16* __restrict__ Ucg,
        const float* __restrict__ barr,
        float* __restrict__ o1g, u16* __restrict__ DTg){
    __shared__ __align__(16) u16 WcS[64*128];
    __shared__ __align__(16) u16 Ks[64*128];
    __shared__ __align__(16) u16 Qs[64*128];
    __shared__ __align__(16) u16 KpT[128*72];
    __shared__ __align__(16) u16 UcS[64*32];
    __shared__ __align__(16) u16 DT[32*72];
    __shared__ float Sm[128*32];
    __shared__ __align__(16) u16 STh[32*136];
    __shared__ __align__(16) u16 STl[32*136];
    __shared__ float bvv[64], esc[64];
    const int tid = threadIdx.x, lane = tid&63, wave = tid>>6;
    const int lr = lane&15, lg = lane>>4;
    const int blk = blockIdx.x;
    const int bh = blk & 31, vs = blk >> 5;
    const int b = bh>>4, h = bh&15, v0 = vs*32;
    const u16* qgb = mixed + (size_t)b*T_SEQ*CONV_CH + h*128;
    const u16* kgb = qgb + KD;

    for (int i=tid; i<128*32; i+=256) Sm[i] = 0.f;
    for (int i=tid; i<32*136; i+=256){ STh[i]=0; STl[i]=0; }
    __syncthreads();

    for (int ci=0; ci<64; ci++){
        const int chunk = bh*64 + ci;
        const size_t rowbase = (size_t)b*T_SEQ + ci*64;
        #pragma unroll
        for (int pass=0; pass<4; pass++){
            gl_lds16(Wcg + (size_t)chunk*8192 + pass*2048 + tid*8, WcS + pass*2048 + tid*8);
            int row = pass*16 + (tid>>4), co = (tid&15)*8;
            gl_lds16(kgb + ((size_t)(ci*64) + row)*CONV_CH + co, Ks + row*128 + co);
            gl_lds16(qgb + ((size_t)(ci*64) + row)*CONV_CH + co, Qs + row*128 + co);
        }
        { int row = tid>>2, c8 = (tid&3)*8;
          *(uint4*)&UcS[row*32 + c8] = *(const uint4*)(Ucg + (size_t)chunk*8192 + row*128 + v0 + c8); }
        if (tid<64) bvv[tid] = barr[(size_t)chunk*64 + tid];
        __syncthreads();
        if (tid<64) esc[tid] = __expf(bvv[63] - bvv[tid]);
        // Delta = Uc - Wc@S0 -> DT [v][t]
        #pragma unroll
        for (int i=0;i<2;i++){
            int tile = wave*2 + i, tm = tile>>1, tn = tile&1;
            f32x4 acc = {};
            #pragma unroll
            for (int kk=0;kk<4;kk++){
                bf16x8 af = frag(WcS, tm*16+lr, 128, kk*32+lg*8);
                acc = __builtin_amdgcn_mfma_f32_16x16x32_bf16(af, frag(STh, tn*16+lr, 136, kk*32+lg*8), acc, 0,0,0);
                acc = __builtin_amdgcn_mfma_f32_16x16x32_bf16(af, frag(STl, tn*16+lr, 136, kk*32+lg*8), acc, 0,0,0);
            }
            #pragma unroll
            for (int r=0;r<4;r++){
                int t = tm*16+lg*4+r, vv = tn*16+lr;
                DT[vv*72 + t] = f2bf(bf2f(UcS[t*32+vv]) - acc[r]);
            }
        }
        // o1 = e^{b_t} * (Q @ S0), exact S0 via hi+lo
        #pragma unroll
        for (int i=0;i<2;i++){
            int tile = wave*2 + i, tm = tile>>1, tn = tile&1;
            f32x4 acc = {};
            #pragma unroll
            for (int kk=0;kk<4;kk++){
                bf16x8 af = frag(Qs, tm*16+lr, 128, kk*32+lg*8);
                acc = __builtin_amdgcn_mfma_f32_16x16x32_bf16(af, frag(STh, tn*16+lr, 136, kk*32+lg*8), acc, 0,0,0);
                acc = __builtin_amdgcn_mfma_f32_16x16x32_bf16(af, frag(STl, tn*16+lr, 136, kk*32+lg*8), acc, 0,0,0);
            }
            #pragma unroll
            for (int r=0;r<4;r++){
                int t = tm*16+lg*4+r, vv = tn*16+lr;
                o1g[((rowbase + t)*NH + h)*DKH + v0 + vv] = acc[r]*__expf(bvv[t]);
            }
        }
        __syncthreads();
        for (int i=tid; i<8192; i+=256){
            int t = i>>7, k = i&127;
            KpT[(size_t)k*72 + t] = f2bf(bf2f(Ks[t*128 + k]) * esc[t]);
        }
        { int vv = tid>>3, c = (tid&7)*8;
          *(uint4*)(DTg + (size_t)chunk*8192 + (size_t)(v0+vv)*64 + c) = *(const uint4*)&DT[vv*72 + c]; }
        __syncthreads();
        float lamC = __expf(bvv[63]);
        #pragma unroll
        for (int i=0;i<4;i++){
            int tile = wave*4 + i, tm = tile>>1, tn = tile&1;
            f32x4 acc;
            #pragma unroll
            for (int r=0;r<4;r++) acc[r] = lamC * Sm[(tm*16+lg*4+r)*32 + tn*16+lr];
            #pragma unroll
            for (int kk=0;kk<2;kk++)
                acc = __builtin_amdgcn_mfma_f32_16x16x32_bf16(
                    frag(KpT, tm*16+lr, 72, kk*32+lg*8),
                    frag(DT,  tn*16+lr, 72, kk*32+lg*8), acc, 0,0,0);
            #pragma unroll
            for (int r=0;r<4;r++){
                int k = tm*16+lg*4+r, vv = tn*16+lr;
                Sm[k*32+vv] = acc[r];
                u16 hi = f2bf(acc[r]);
                STh[vv*136 + k] = hi;
                STl[vv*136 + k] = f2bf(acc[r] - bf2f(hi));
            }
        }
        __syncthreads();
    }
}

// ---------- o = o1 + QKmask @ Delta ----------
__global__ __launch_bounds__(256) void k_out(const u16* __restrict__ mixed,
        const float* __restrict__ barr, const float* __restrict__ o1g,
        const u16* __restrict__ DTg, float* __restrict__ o){
    __shared__ __align__(16) u16 Qs[64*128];
    __shared__ __align__(16) u16 Ks[64*128];
    __shared__ __align__(16) u16 DTs[128*64];
    __shared__ __align__(16) u16 QKm[64*72];
    __shared__ float bvv[64];
    const int tid = threadIdx.x, lane = tid&63, wave = tid>>6;
    const int lr = lane&15, lg = lane>>4;
    const int chunk = blockIdx.x;
    const int ci = chunk&63, bh = chunk>>6, b = bh>>4, h = bh&15;
    const size_t rowbase = (size_t)b*T_SEQ + ci*64;
    const u16* qg = mixed + rowbase*CONV_CH + h*128;
    const u16* kg = qg + KD;
    #pragma unroll
    for (int pass=0; pass<4; pass++){
        int row = pass*16 + (tid>>4), co = (tid&15)*8;
        gl_lds16(qg + (size_t)row*CONV_CH + co, Qs + row*128 + co);
        gl_lds16(kg + (size_t)row*CONV_CH + co, Ks + row*128 + co);
        gl_lds16(DTg + (size_t)chunk*8192 + pass*2048 + tid*8, DTs + pass*2048 + tid*8);
    }
    if (tid<64) bvv[tid] = barr[(size_t)chunk*64 + tid];
    __syncthreads();
    {
        f32x4 acc[4];
        #pragma unroll
        for (int tn=0; tn<4; tn++){
            f32x4 a = {};
            #pragma unroll
            for (int kk=0;kk<4;kk++)
                a = __builtin_amdgcn_mfma_f32_16x16x32_bf16(
                    frag(Qs, wave*16+lr, 128, kk*32+lg*8),
                    frag(Ks, tn*16+lr, 128, kk*32+lg*8), a, 0,0,0);
            acc[tn] = a;
        }
        #pragma unroll
        for (int tn=0;tn<4;tn++)
            #pragma unroll
            for (int r=0;r<4;r++){
                int t = wave*16+lg*4+r, s = tn*16+lr;
                float val = (t>=s) ? acc[tn][r]*__expf(bvv[t]-bvv[s]) : 0.f;
                QKm[t*72+s] = f2bf(val);
            }
    }
    __syncthreads();
    f32x4 acc[8] = {};
    #pragma unroll
    for (int kk=0;kk<2;kk++){
        bf16x8 af = frag(QKm, wave*16+lr, 72, kk*32+lg*8);
        #pragma unroll
        for (int tn=0;tn<8;tn++)
            acc[tn] = __builtin_amdgcn_mfma_f32_16x16x32_bf16(af, frag(DTs, tn*16+lr, 64, kk*32+lg*8), acc[tn], 0,0,0);
    }
    #pragma unroll
    for (int tn=0;tn<8;tn++)
        #pragma unroll
        for (int r=0;r<4;r++){
            int t = wave*16+lg*4+r, v = tn*16+lr;
            size_t idx = ((rowbase + t)*NH + h)*DKH + v;
            o[idx] = o1g[idx] + acc[tn][r];
        }
}

// ---------- x = RMSNorm(o * silu(z)) * norm_w, cast bf16 ----------
__global__ void k_gatenorm(const float* __restrict__ o, const u16* __restrict__ zbuf,
                           const float* __restrict__ norm_w, u16* __restrict__ x){
    int gw   = blockIdx.x*4 + (threadIdx.x>>6);
    int lane = threadIdx.x & 63;
    int bt = gw >> 4, h = gw & 15;
    const float* opr = o + ((size_t)bt*NH + h)*DKH + lane*2;
    const u16* zp = zbuf + (size_t)bt*VD + h*DKH + lane*2;
    float o0 = opr[0], o1 = opr[1];
    u32 zu = *(const u32*)zp;
    float z0 = bflo(zu), z1 = bfhi(zu);
    float x0 = o0 * (z0/(1.f+__expf(-z0)));
    float x1 = o1 * (z1/(1.f+__expf(-z1)));
    float ss = x0*x0 + x1*x1;
    #pragma unroll
    for (int m=1;m<64;m<<=1) ss += __shfl_xor(ss, m, 64);
    float sc = rsqrtf(ss*(1.f/128.f) + 1e-6f);
    x0 *= sc*norm_w[lane*2]; x1 *= sc*norm_w[lane*2+1];
    ((u32*)x)[(size_t)bt*(VD/2) + h*(DKH/2) + lane] = (u32)f2bf(x0) | ((u32)f2bf(x1)<<16);
}

extern "C" void kernel_launch(void* const* d_in, const int* in_sizes, int n_in,
                              void* d_out, int out_size, void* d_ws, size_t ws_size,
                              hipStream_t stream){
    (void)in_sizes; (void)n_in; (void)out_size; (void)ws_size;
    const float* hidden = (const float*)d_in[0];
    const float* W_qkvz = (const float*)d_in[1];
    const float* W_ba   = (const float*)d_in[2];
    const float* conv_w = (const float*)d_in[3];
    const float* conv_b = (const float*)d_in[4];
    const float* dt_bias= (const float*)d_in[5];
    const float* A_log  = (const float*)d_in[6];
    const float* norm_w = (const float*)d_in[7];
    const float* W_out  = (const float*)d_in[8];
    float* out = (float*)d_out;

    char* ws = (char*)d_ws;
    size_t off = 0;
    auto alloc = [&](size_t bytes)->char*{ char* p = ws + off; off += (bytes + 255) & ~(size_t)255; return p; };
    // Pool A (100.66 MB): h_bf|WqT -> Wcg|Ucg|DTg -> o|DTg
    char* poolA = alloc(100663296);
    u16*   h_bf = (u16*)poolA;
    u16*   WqT  = (u16*)(poolA + 50331648);
    u16*   Wcg  = (u16*)poolA;
    u16*   Ucg  = (u16*)(poolA + 33554432);
    u16*   DTg  = (u16*)(poolA + 67108864);
    float* o_b  = (float*)poolA;
    // Pool B (100.66 MB): qkv_lin -> o1g|barr -> x|barr
    char* poolB = alloc(100663296);
    u16*   qkv_lin = (u16*)poolB;
    float* o1g  = (float*)poolB;
    float* barr = (float*)(poolB + 67108864);
    u16*   x_b  = (u16*)poolB;
    u16*   WoT  = (u16*)  alloc((size_t)HID*VD*2);        // 12.6 MB
    u16*   zbuf = (u16*)  alloc((size_t)MROWS*VD*2);      // 33.55 MB
    u16*   mixed= (u16*)  alloc((size_t)MROWS*CONV_CH*2); // 100.66 MB
    float2* be_b= (float2*)alloc((size_t)MROWS*NH*8);     // 1.05 MB
    // total 349.2 MB == round-2 proven footprint

    k_cast<<<2048,256,0,stream>>>(hidden, h_bf, MROWS*HID/4);
    k_transpose_cast<<<(HID/32)*(N_QKVZ/32),256,0,stream>>>(W_qkvz, WqT, HID, N_QKVZ);
    k_transpose_cast<<<(VD/32)*(HID/32),256,0,stream>>>(W_out, WoT, VD, HID);
    k_gemm_bt<true><<<dim3(N_QKVZ/128, MROWS/128),256,0,stream>>>(h_bf, WqT, qkv_lin, zbuf,
                         MROWS, N_QKVZ, HID, CONV_CH, CONV_CH, VD);
    k_ba<<<MROWS/8,256,0,stream>>>(hidden, W_ba, dt_bias, A_log, be_b);
    k_conv_silu<<<(long)MROWS*CONV_CH/256,256,0,stream>>>(qkv_lin, conv_w, conv_b, mixed);
    k_qknorm<<<MROWS*32/4,256,0,stream>>>(mixed);
    k_prep<<<2048,512,0,stream>>>(mixed, be_b, Wcg, Ucg, barr);
    k_seq<<<128,256,0,stream>>>(mixed, Wcg, Ucg, barr, o1g, DTg);
    k_out<<<2048,256,0,stream>>>(mixed, barr, o1g, DTg, o_b);
    k_gatenorm<<<MROWS*NH/4,256,0,stream>>>(o_b, zbuf, norm_w, x_b);
    k_gemm_bt<false><<<dim3(HID/128, MROWS/128),256,0,stream>>>(x_b, WoT, out, nullptr,
                         MROWS, HID, VD, 1<<30, HID, 0);
}